// Round 5
// baseline (728.819 us; speedup 1.0000x reference)
//
#include <hip/hip_runtime.h>
#include <hip/hip_bf16.h>

// CRF-as-RNN mean-field on MI355X. B=2, L=21, C=3, H=W=96, N=9216, NITERS=5.
//
// w[n][m] = exp2(gs[m] + f_n . fs[m])  (log2e pre-scaled; row factor cancels
// under row normalization). Per iter:
//   P[n][l] = sum_m w[n][m]*MQ[l][m]  via bf16 MFMA 16x16x32.
// A-fragment (w) generated in registers (R3-validated mapping
// A[row=lane&15][k=(lane>>4)*8+j]); B-tile staged in LDS in FRAGMENT LAYOUT
// with XOR swizzle (conflict-free both sides), register-double-buffered one
// chunk ahead; FS loads software-pipelined one kstep ahead (R4 was
// latency-bound at VALUBusy=35%).
// MQ padded to 32 channels: ch21 = 1.0 -> P[.,21] = rowsum (free), ch22..31=0.
// msg = P/P[21]; Q = softmax_l(-(E0+msg)); MQ = Mu@Q (bf16).

#define BB 2
#define LL 21
#define LCH 32              // padded channel count of MQ
#define LLP 22              // channels stored in Ppart (21 + rowsum)
#define NNPX 9216
#define NITERS 5
#define LOG2E 1.4426950408889634f

typedef __attribute__((ext_vector_type(8))) short short8;
typedef __attribute__((ext_vector_type(4))) float f32x4;

static __device__ inline unsigned int pk_bf16(float a, float b) {
    __hip_bfloat162 h = __float22bfloat162_rn(make_float2(a, b));
    unsigned int u;
    __builtin_memcpy(&u, &h, 4);
    return u;
}

// ---------------- prep: features + Q0 + MQ0(bf16, padded) ----------------
__global__ __launch_bounds__(256) void k_prep(
        const float* __restrict__ E0, const float* __restrict__ Refs,
        const float* __restrict__ Mu,
        float4* __restrict__ FN, float4* __restrict__ FS,
        __hip_bfloat16* __restrict__ MQ) {
    __shared__ float muS[LL * LL];
    for (int i = threadIdx.x; i < LL * LL; i += 256) muS[i] = Mu[i];
    __syncthreads();

    int idx = blockIdx.x * 256 + threadIdx.x;      // b*N + n
    int b = idx / NNPX, n = idx % NNPX;

    const float* rb = Refs + (size_t)b * 3 * NNPX + n;
    float r0 = rb[0], r1 = rb[NNPX], r2 = rb[2 * NNPX];
    FN[idx] = make_float4(r0, r1, r2, 0.f);
    float g = -0.5f * (r0 * r0 + r1 * r1 + r2 * r2);
    FS[idx] = make_float4(g * LOG2E, r0 * LOG2E, r1 * LOG2E, r2 * LOG2E);

    const float* eb = E0 + (size_t)b * LL * NNPX + n;
    float x[LL];
    float mx = -1e30f;
    for (int l = 0; l < LL; ++l) { x[l] = -eb[(size_t)l * NNPX]; mx = fmaxf(mx, x[l]); }
    float s = 0.f;
    for (int l = 0; l < LL; ++l) { x[l] = __builtin_amdgcn_exp2f((x[l] - mx) * LOG2E); s += x[l]; }
    float rs = __builtin_amdgcn_rcpf(s);
    for (int l = 0; l < LL; ++l) x[l] *= rs;

    __hip_bfloat16* mq = MQ + (size_t)b * LCH * NNPX + n;
    for (int k = 0; k < LL; ++k) {
        float a = 0.f;
        for (int l = 0; l < LL; ++l) a += muS[k * LL + l] * x[l];
        mq[(size_t)k * NNPX] = __float2bfloat16(a);
    }
    mq[(size_t)21 * NNPX] = __float2bfloat16(1.0f);    // ones column -> rowsum
    for (int k = 22; k < LCH; ++k) mq[(size_t)k * NNPX] = __float2bfloat16(0.0f);
}

// ---------------- accumulate via MFMA: reg A-gen + swizzled-LDS B ----------------
// grid (288, S): blockIdx.x = b*144 + n-tile(64 rows); wave handles 16 rows.
// m in chunks of 256 (36 chunks); split s takes chunks s, s+S, ...
// LDS B layout: 16B slot index = buf*512 + ks*64 + (fragLane ^ ks),
//   buf = (l>=16), fragLane = 16*q + (l&15), ks = m-seg>>2, q = m-seg&3.
// Reads per kstep are 1KB-contiguous (lane^ks is a lane permutation);
// writes spread min-conflict. B regs double-buffered one chunk ahead;
// FS (global, L1-hot) pipelined one kstep ahead.
__global__ __launch_bounds__(256, 4) void k_accum(
        const float4* __restrict__ FS, const float4* __restrict__ FN,
        const unsigned short* __restrict__ MQbf, float* __restrict__ Ppart, int S) {
    __shared__ __align__(16) uint4 Bl[1024];   // 16 KB

    int t = threadIdx.x;
    int rb = blockIdx.x;
    int s  = blockIdx.y;
    int b  = rb / 144;
    int n0 = (rb % 144) * 64;
    int wv = t >> 6, lane = t & 63;
    int col = lane & 15, q = lane >> 4;

    float4 fn = FN[b * NNPX + n0 + wv * 16 + col];
    const float4* fsb = FS + (size_t)b * NNPX;
    const unsigned short* mqb = MQbf + (size_t)b * LCH * NNPX;

    // staging map for thread t, element i: e = t + 256*i
    int slot[4]; size_t gsrc[4];
    for (int i = 0; i < 4; ++i) {
        int e = t + 256 * i;
        int l = e >> 5, sg = e & 31;
        int ks = sg >> 2, qq = sg & 3;
        slot[i] = (l >= 16 ? 512 : 0) + ks * 64 + ((16 * qq + (l & 15)) ^ ks);
        gsrc[i] = (size_t)l * NNPX + sg * 8;
    }

    f32x4 acc0 = {0.f, 0.f, 0.f, 0.f};   // l = 0..15
    f32x4 acc1 = {0.f, 0.f, 0.f, 0.f};   // l = 16..31 (21 = rowsum)

    // prefetch B for first chunk
    uint4 pre[4];
    {
        int m0 = s * 256;
        for (int i = 0; i < 4; ++i) pre[i] = *(const uint4*)&mqb[gsrc[i] + m0];
    }

    for (int c = s; c < 36; c += S) {
        int m0 = c * 256;
        __syncthreads();   // previous chunk's fragment reads done
        for (int i = 0; i < 4; ++i) Bl[slot[i]] = pre[i];
        // issue next chunk's B loads (latency hidden behind 8 ksteps)
        int cn = c + S;
        if (cn < 36) {
            int mn = cn * 256;
            for (int i = 0; i < 4; ++i) pre[i] = *(const uint4*)&mqb[gsrc[i] + mn];
        }
        __syncthreads();   // B staged

        // FS pipeline: Fc = current kstep, Fn = next
        float4 Fc[8], Fn[8];
        {
            int kb = m0 + q * 8;
            #pragma unroll
            for (int j = 0; j < 8; ++j) Fc[j] = fsb[kb + j];
        }
        #pragma unroll
        for (int ks = 0; ks < 8; ++ks) {
            if (ks < 7) {
                int kb = m0 + (ks + 1) * 32 + q * 8;
                #pragma unroll
                for (int j = 0; j < 8; ++j) Fn[j] = fsb[kb + j];
            }
            float w0 = __builtin_amdgcn_exp2f(Fc[0].x + fn.x * Fc[0].y + fn.y * Fc[0].z + fn.z * Fc[0].w);
            float w1 = __builtin_amdgcn_exp2f(Fc[1].x + fn.x * Fc[1].y + fn.y * Fc[1].z + fn.z * Fc[1].w);
            float w2 = __builtin_amdgcn_exp2f(Fc[2].x + fn.x * Fc[2].y + fn.y * Fc[2].z + fn.z * Fc[2].w);
            float w3 = __builtin_amdgcn_exp2f(Fc[3].x + fn.x * Fc[3].y + fn.y * Fc[3].z + fn.z * Fc[3].w);
            float w4 = __builtin_amdgcn_exp2f(Fc[4].x + fn.x * Fc[4].y + fn.y * Fc[4].z + fn.z * Fc[4].w);
            float w5 = __builtin_amdgcn_exp2f(Fc[5].x + fn.x * Fc[5].y + fn.y * Fc[5].z + fn.z * Fc[5].w);
            float w6 = __builtin_amdgcn_exp2f(Fc[6].x + fn.x * Fc[6].y + fn.y * Fc[6].z + fn.z * Fc[6].w);
            float w7 = __builtin_amdgcn_exp2f(Fc[7].x + fn.x * Fc[7].y + fn.y * Fc[7].z + fn.z * Fc[7].w);
            union { unsigned int u[4]; short8 v; } af;
            af.u[0] = pk_bf16(w0, w1);
            af.u[1] = pk_bf16(w2, w3);
            af.u[2] = pk_bf16(w4, w5);
            af.u[3] = pk_bf16(w6, w7);
            int sl = ks * 64 + (lane ^ ks);
            short8 bf0 = *(const short8*)&Bl[sl];
            short8 bf1 = *(const short8*)&Bl[512 + sl];
            acc0 = __builtin_amdgcn_mfma_f32_16x16x32_bf16(af.v, bf0, acc0, 0, 0, 0);
            acc1 = __builtin_amdgcn_mfma_f32_16x16x32_bf16(af.v, bf1, acc1, 0, 0, 0);
            #pragma unroll
            for (int j = 0; j < 8; ++j) Fc[j] = Fn[j];
        }
    }

    // epilogue: C layout col=lane&15, row=(lane>>4)*4+reg  (validated R2/R3/R4)
    float* pp = Ppart + (size_t)(s * BB + b) * LLP * NNPX;
    int nb = n0 + wv * 16 + q * 4;
    for (int r = 0; r < 4; ++r) {
        pp[(size_t)col * NNPX + nb + r] = acc0[r];
        if (col < LLP - 16) pp[(size_t)(16 + col) * NNPX + nb + r] = acc1[r];
    }
}

// ---------------- reduce partials + softmax + Potts mix ----------------
template <bool LAST>
__global__ __launch_bounds__(256) void k_softmax(
        const float* __restrict__ E0, const float* __restrict__ Ppart,
        const float* __restrict__ Mu,
        __hip_bfloat16* __restrict__ MQ, float* __restrict__ Out, int S) {
    __shared__ float muS[LL * LL];
    for (int i = threadIdx.x; i < LL * LL; i += 256) muS[i] = Mu[i];
    __syncthreads();

    int idx = blockIdx.x * 256 + threadIdx.x;
    int b = idx / NNPX, n = idx % NNPX;

    float P[LLP];
    for (int l = 0; l < LLP; ++l) P[l] = 0.f;
    for (int s = 0; s < S; ++s) {
        const float* pp = Ppart + (size_t)(s * BB + b) * LLP * NNPX + n;
        for (int l = 0; l < LLP; ++l) P[l] += pp[(size_t)l * NNPX];
    }
    float rinv = __builtin_amdgcn_rcpf(P[21]);   // rowsum channel

    const float* eb = E0 + (size_t)b * LL * NNPX + n;
    float mx = -1e30f;
    for (int l = 0; l < LL; ++l) {
        P[l] = -(eb[(size_t)l * NNPX] + P[l] * rinv);
        mx = fmaxf(mx, P[l]);
    }
    float ssum = 0.f;
    for (int l = 0; l < LL; ++l) { P[l] = __builtin_amdgcn_exp2f((P[l] - mx) * LOG2E); ssum += P[l]; }
    float rs = __builtin_amdgcn_rcpf(ssum);
    for (int l = 0; l < LL; ++l) P[l] *= rs;

    if (LAST) {
        float* ob = Out + (size_t)b * LL * NNPX + n;
        for (int l = 0; l < LL; ++l) ob[(size_t)l * NNPX] = P[l];
    } else {
        __hip_bfloat16* mq = MQ + (size_t)b * LCH * NNPX + n;
        for (int k = 0; k < LL; ++k) {
            float a = 0.f;
            for (int l = 0; l < LL; ++l) a += muS[k * LL + l] * P[l];
            mq[(size_t)k * NNPX] = __float2bfloat16(a);
        }
        // channels 21..31 keep their k_prep values (1.0, zeros)
    }
}

extern "C" void kernel_launch(void* const* d_in, const int* in_sizes, int n_in,
                              void* d_out, int out_size, void* d_ws, size_t ws_size,
                              hipStream_t stream) {
    const float* E0   = (const float*)d_in[0];
    const float* Refs = (const float*)d_in[1];
    const float* Mu   = (const float*)d_in[2];
    float* out = (float*)d_out;

    char* w = (char*)d_ws;
    size_t off = 0;
    auto alloc = [&](size_t bytes) {
        void* p = w + off;
        off += (bytes + 255) & ~(size_t)255;
        return p;
    };
    float4* FN = (float4*)alloc((size_t)BB * NNPX * sizeof(float4));
    float4* FS = (float4*)alloc((size_t)BB * NNPX * sizeof(float4));
    __hip_bfloat16* MQbf = (__hip_bfloat16*)alloc((size_t)BB * LCH * NNPX * sizeof(__hip_bfloat16));

    // m-split S (divisor of 36, cap 6) whose partial buffer fits in remaining ws
    size_t per = (size_t)BB * LLP * NNPX * sizeof(float);
    size_t avail = ws_size > off ? ws_size - off : 0;
    int Smax = (int)(avail / (per + 256));
    static const int divs[] = {6, 4, 3, 2, 1};
    int S = 1;
    for (int i = 0; i < 5; ++i) if (divs[i] <= Smax) { S = divs[i]; break; }
    float* Ppart = (float*)alloc((size_t)S * per);

    k_prep<<<BB * NNPX / 256, 256, 0, stream>>>(E0, Refs, Mu, FN, FS, MQbf);
    for (int it = 0; it < NITERS; ++it) {
        k_accum<<<dim3(288, S), 256, 0, stream>>>(FS, FN, (const unsigned short*)MQbf, Ppart, S);
        if (it == NITERS - 1)
            k_softmax<true><<<BB * NNPX / 256, 256, 0, stream>>>(E0, Ppart, Mu, MQbf, out, S);
        else
            k_softmax<false><<<BB * NNPX / 256, 256, 0, stream>>>(E0, Ppart, Mu, MQbf, out, S);
    }
}

// Round 7
// 602.518 us; speedup vs baseline: 1.2096x; 1.2096x over previous
//
#include <hip/hip_runtime.h>
#include <hip/hip_bf16.h>
#include <hip/hip_fp16.h>

// CRF-as-RNN mean-field on MI355X. B=2, L=21, C=3, H=W=96, N=9216, NITERS=5.
//
// w[n][m] = exp2(g'[m] + f_n . f'[m] + c_n), all log2e-pre-scaled;
// c_n = -0.5|f_n|^2 log2e bounds w<=1 (row scaling cancels under the
// normalization, and keeps w f16-representable for the MFMA A-fragment).
// Per iter: P[n][l] = sum_m w[n][m]*MQ[l][m] via f16 MFMA 16x16x32.
//   - dot computed with v_pk_fma_f16 (FS stored as f16 planes, 8-m groups)
//   - exp in f32 (v_exp_f32), packed to f16 via v_cvt_pkrtz
//   - A-fragment generated in registers (R3-validated layout)
//   - B-tile (MQ, f16) staged in LDS SLOT-LINEAR (thread t <-> slot t):
//     conflict-free writes AND reads (R4 pad / R5 xor both had conflicts)
//   - B regs prefetched one chunk ahead; FS group prefetched one kstep ahead
//     (small: 32 VGPRs total -- R5's 64-reg pipeline + launch_bounds(,4)
//     caused scratch spill, the 136us regression)
// MQ padded to 32 ch: ch21 = 1.0 -> P[.,21] = rowsum free, ch22..31 = 0.
// msg = P/P[21]; Q = softmax_l(-(E0+msg)); MQ = Mu@Q (f16).

#define BB 2
#define LL 21
#define LCH 32
#define LLP 22
#define NNPX 9216
#define NGRP 1152           // NNPX/8 groups of 8 m
#define NITERS 5
#define LOG2E 1.4426950408889634f

typedef __attribute__((ext_vector_type(8))) _Float16 half8;
typedef __attribute__((ext_vector_type(4))) float f32x4;

// ---------------- prep: features + Q0 + MQ0(f16, padded) ----------------
__global__ __launch_bounds__(256) void k_prep(
        const float* __restrict__ E0, const float* __restrict__ Refs,
        const float* __restrict__ Mu,
        float4* __restrict__ FN, __half* __restrict__ FSH,
        __half* __restrict__ MQ) {
    __shared__ float muS[LL * LL];
    for (int i = threadIdx.x; i < LL * LL; i += 256) muS[i] = Mu[i];
    __syncthreads();

    int idx = blockIdx.x * 256 + threadIdx.x;      // b*N + n
    int b = idx / NNPX, n = idx % NNPX;

    const float* rb = Refs + (size_t)b * 3 * NNPX + n;
    float r0 = rb[0], r1 = rb[NNPX], r2 = rb[2 * NNPX];
    float gp = -0.5f * (r0 * r0 + r1 * r1 + r2 * r2) * LOG2E;
    FN[idx] = make_float4(r0, r1, r2, gp);         // .w = c_n

    // FS planes: group g = n>>3, element e = n&7; [g][plane][e] f16
    __half* fsh = FSH + (((size_t)b * NGRP + (n >> 3)) << 5) + (n & 7);
    fsh[0]  = __float2half(gp);
    fsh[8]  = __float2half(r0 * LOG2E);
    fsh[16] = __float2half(r1 * LOG2E);
    fsh[24] = __float2half(r2 * LOG2E);

    const float* eb = E0 + (size_t)b * LL * NNPX + n;
    float x[LL];
    float mx = -1e30f;
    for (int l = 0; l < LL; ++l) { x[l] = -eb[(size_t)l * NNPX]; mx = fmaxf(mx, x[l]); }
    float s = 0.f;
    for (int l = 0; l < LL; ++l) { x[l] = __builtin_amdgcn_exp2f((x[l] - mx) * LOG2E); s += x[l]; }
    float rs = __builtin_amdgcn_rcpf(s);
    for (int l = 0; l < LL; ++l) x[l] *= rs;

    __half* mq = MQ + (size_t)b * LCH * NNPX + n;
    for (int k = 0; k < LL; ++k) {
        float a = 0.f;
        for (int l = 0; l < LL; ++l) a += muS[k * LL + l] * x[l];
        mq[(size_t)k * NNPX] = __float2half(a);
    }
    mq[(size_t)21 * NNPX] = __float2half(1.0f);    // ones column -> rowsum
    for (int k = 22; k < LCH; ++k) mq[(size_t)k * NNPX] = __float2half(0.0f);
}

// ---------------- accumulate via f16 MFMA ----------------
// grid (288, S): blockIdx.x = b*144 + n-tile(64 rows); wave handles 16 rows.
// m in chunks of 256 (36 chunks); split s takes chunks s, s+S, ...
// LDS B slot s (16B): buf=s>>9, ks=(s>>6)&7, fragLane=s&63 (q=fl>>4,col=fl&15)
//   holds MQ[l=buf*16+col][m0+ks*32+q*8 .. +7] as f16x8. Thread t writes
//   slots t,t+256,t+512,t+768 (linear -> conflict-free); kstep reads
//   slot ks*64+lane (+512) -> lane-consecutive -> conflict-free.
__global__ __launch_bounds__(256) void k_accum(
        const uint4* __restrict__ FSH4, const float4* __restrict__ FN,
        const __half* __restrict__ MQh, float* __restrict__ Ppart, int S) {
    __shared__ __align__(16) uint4 Bl[1024];   // 16 KB

    int t = threadIdx.x;
    int rb = blockIdx.x;
    int s  = blockIdx.y;
    int b  = rb / 144;
    int n0 = (rb % 144) * 64;
    int wv = t >> 6, lane = t & 63;
    int col = lane & 15, q = lane >> 4;

    float4 fn = FN[b * NNPX + n0 + wv * 16 + col];
    __half2 fnx2 = __float2half2_rn(fn.x);
    __half2 fny2 = __float2half2_rn(fn.y);
    __half2 fnz2 = __float2half2_rn(fn.z);
    float cn = fn.w;

    const uint4* fshb = FSH4 + (size_t)b * NGRP * 4;
    const __half* mqb = MQh + (size_t)b * LCH * NNPX;

    // B staging map: thread t, element i -> slot e = t+256i (linear)
    size_t gsrc[4];
    for (int i = 0; i < 4; ++i) {
        int e = t + 256 * i;
        int buf = e >> 9, ks = (e >> 6) & 7, fl = e & 63;
        int qq = fl >> 4, cl = fl & 15;
        gsrc[i] = (size_t)(buf * 16 + cl) * NNPX + ks * 32 + qq * 8;
    }

    f32x4 acc0 = {0.f, 0.f, 0.f, 0.f};   // l = 0..15
    f32x4 acc1 = {0.f, 0.f, 0.f, 0.f};   // l = 16..31 (21 = rowsum)

    // prefetch B for first chunk
    uint4 pre[4];
    for (int i = 0; i < 4; ++i) pre[i] = *(const uint4*)&mqb[gsrc[i] + s * 256];

    union U { uint4 v; __half2 h[4]; };

    for (int c = s; c < 36; c += S) {
        __syncthreads();   // previous chunk's fragment reads done
        for (int i = 0; i < 4; ++i) Bl[t + 256 * i] = pre[i];
        int cn_ = c + S;
        if (cn_ < 36)
            for (int i = 0; i < 4; ++i) pre[i] = *(const uint4*)&mqb[gsrc[i] + cn_ * 256];
        __syncthreads();   // B staged

        int grp0 = c * 32 + q;             // this lane's group at ks=0
        U Gc[4], Gn[4];
        #pragma unroll
        for (int p = 0; p < 4; ++p) Gc[p].v = fshb[(size_t)grp0 * 4 + p];

        #pragma unroll
        for (int ks = 0; ks < 8; ++ks) {
            if (ks < 7) {
                int grp = grp0 + (ks + 1) * 4;
                #pragma unroll
                for (int p = 0; p < 4; ++p) Gn[p].v = fshb[(size_t)grp * 4 + p];
            }
            union { unsigned int u[4]; half8 v; } af;
            #pragma unroll
            for (int j = 0; j < 4; ++j) {
                __half2 tt = __hfma2(Gc[1].h[j], fnx2, Gc[0].h[j]);
                tt = __hfma2(Gc[2].h[j], fny2, tt);
                tt = __hfma2(Gc[3].h[j], fnz2, tt);
                float2 tf = __half22float2(tt);
                float w0 = __builtin_amdgcn_exp2f(tf.x + cn);
                float w1 = __builtin_amdgcn_exp2f(tf.y + cn);
                __typeof__(__builtin_amdgcn_cvt_pkrtz(0.f, 0.f)) pk =
                    __builtin_amdgcn_cvt_pkrtz(w0, w1);
                __builtin_memcpy(&af.u[j], &pk, 4);
            }
            union { uint4 v; half8 h; } b0, b1;
            b0.v = Bl[ks * 64 + lane];
            b1.v = Bl[512 + ks * 64 + lane];
            acc0 = __builtin_amdgcn_mfma_f32_16x16x32_f16(af.v, b0.h, acc0, 0, 0, 0);
            acc1 = __builtin_amdgcn_mfma_f32_16x16x32_f16(af.v, b1.h, acc1, 0, 0, 0);
            #pragma unroll
            for (int p = 0; p < 4; ++p) Gc[p] = Gn[p];
        }
    }

    // epilogue: C layout col=lane&15, row=(lane>>4)*4+reg  (validated R2-R5)
    float* pp = Ppart + (size_t)(s * BB + b) * LLP * NNPX;
    int nb = n0 + wv * 16 + q * 4;
    for (int r = 0; r < 4; ++r) {
        pp[(size_t)col * NNPX + nb + r] = acc0[r];
        if (col < LLP - 16) pp[(size_t)(16 + col) * NNPX + nb + r] = acc1[r];
    }
}

// ---------------- reduce partials + softmax + Potts mix ----------------
template <bool LAST>
__global__ __launch_bounds__(256) void k_softmax(
        const float* __restrict__ E0, const float* __restrict__ Ppart,
        const float* __restrict__ Mu,
        __half* __restrict__ MQ, float* __restrict__ Out, int S) {
    __shared__ float muS[LL * LL];
    for (int i = threadIdx.x; i < LL * LL; i += 256) muS[i] = Mu[i];
    __syncthreads();

    int idx = blockIdx.x * 256 + threadIdx.x;
    int b = idx / NNPX, n = idx % NNPX;

    float P[LLP];
    for (int l = 0; l < LLP; ++l) P[l] = 0.f;
    for (int s = 0; s < S; ++s) {
        const float* pp = Ppart + (size_t)(s * BB + b) * LLP * NNPX + n;
        for (int l = 0; l < LLP; ++l) P[l] += pp[(size_t)l * NNPX];
    }
    float rinv = __builtin_amdgcn_rcpf(P[21]);   // rowsum channel

    const float* eb = E0 + (size_t)b * LL * NNPX + n;
    float mx = -1e30f;
    for (int l = 0; l < LL; ++l) {
        P[l] = -(eb[(size_t)l * NNPX] + P[l] * rinv);
        mx = fmaxf(mx, P[l]);
    }
    float ssum = 0.f;
    for (int l = 0; l < LL; ++l) { P[l] = __builtin_amdgcn_exp2f((P[l] - mx) * LOG2E); ssum += P[l]; }
    float rs = __builtin_amdgcn_rcpf(ssum);
    for (int l = 0; l < LL; ++l) P[l] *= rs;

    if (LAST) {
        float* ob = Out + (size_t)b * LL * NNPX + n;
        for (int l = 0; l < LL; ++l) ob[(size_t)l * NNPX] = P[l];
    } else {
        __half* mq = MQ + (size_t)b * LCH * NNPX + n;
        for (int k = 0; k < LL; ++k) {
            float a = 0.f;
            for (int l = 0; l < LL; ++l) a += muS[k * LL + l] * P[l];
            mq[(size_t)k * NNPX] = __float2half(a);
        }
        // channels 21..31 keep their k_prep values (1.0, zeros)
    }
}

extern "C" void kernel_launch(void* const* d_in, const int* in_sizes, int n_in,
                              void* d_out, int out_size, void* d_ws, size_t ws_size,
                              hipStream_t stream) {
    const float* E0   = (const float*)d_in[0];
    const float* Refs = (const float*)d_in[1];
    const float* Mu   = (const float*)d_in[2];
    float* out = (float*)d_out;

    char* w = (char*)d_ws;
    size_t off = 0;
    auto alloc = [&](size_t bytes) {
        void* p = w + off;
        off += (bytes + 255) & ~(size_t)255;
        return p;
    };
    float4* FN  = (float4*)alloc((size_t)BB * NNPX * sizeof(float4));
    __half* FSH = (__half*)alloc((size_t)BB * NGRP * 32 * sizeof(__half));
    __half* MQh = (__half*)alloc((size_t)BB * LCH * NNPX * sizeof(__half));

    // m-split S (divisor of 36, cap 6) whose partial buffer fits in remaining ws
    size_t per = (size_t)BB * LLP * NNPX * sizeof(float);
    size_t avail = ws_size > off ? ws_size - off : 0;
    int Smax = (int)(avail / (per + 256));
    static const int divs[] = {6, 4, 3, 2, 1};
    int S = 1;
    for (int i = 0; i < 5; ++i) if (divs[i] <= Smax) { S = divs[i]; break; }
    float* Ppart = (float*)alloc((size_t)S * per);

    k_prep<<<BB * NNPX / 256, 256, 0, stream>>>(E0, Refs, Mu, FN, FSH, MQh);
    for (int it = 0; it < NITERS; ++it) {
        k_accum<<<dim3(288, S), 256, 0, stream>>>((const uint4*)FSH, FN, MQh, Ppart, S);
        if (it == NITERS - 1)
            k_softmax<true><<<BB * NNPX / 256, 256, 0, stream>>>(E0, Ppart, Mu, MQh, out, S);
        else
            k_softmax<false><<<BB * NNPX / 256, 256, 0, stream>>>(E0, Ppart, Mu, MQh, out, S);
    }
}